// Round 1
// baseline (239.580 us; speedup 1.0000x reference)
//
#include <hip/hip_runtime.h>
#include <math.h>

#define B_DIM 128
#define N_DIM 512
#define D_DIM 512
#define H_DIM 256
#define K_SEL 8
#define ROWS_PER_WG 64
#define KC 128
#define LDS_STRIDE 68   // 68*4B = 272B: 16B-aligned rows, +4 float pad kills stride-64 bank aliasing

// ---------------- Kernel 1: fused Linear(512->256) + GELU + Linear(256->1) ----------------
// Grid: (B*N)/64 workgroups of 256 threads. Each WG computes 64 rows x 256 hidden cols,
// then reduces to 64 logits. Thread tile: 8 rows x 8 cols (64 fp32 accumulators).
__global__ __launch_bounds__(256) void fused_scorer_kernel(
    const float* __restrict__ X,          // (B*N, 512)
    const float* __restrict__ W1,         // (512, 256) row-major
    const float* __restrict__ b1,         // (256)
    const float* __restrict__ W2,         // (256)
    const float* __restrict__ b2p,        // scalar
    const float* __restrict__ base_logits,// (512)
    float* __restrict__ logits)           // (B*N)
{
    __shared__ __align__(16) float xs[KC][LDS_STRIDE]; // transposed x-tile: xs[k][row]
    const int tid = threadIdx.x;
    const int wg_row0 = blockIdx.x * ROWS_PER_WG;
    const int c0 = (tid & 31) * 8;   // 32 col-groups * 8 = 256 cols
    const int r0 = (tid >> 5) * 8;   // 8 row-groups * 8 = 64 rows

    float acc[8][8];
    #pragma unroll
    for (int i = 0; i < 8; ++i)
        #pragma unroll
        for (int j = 0; j < 8; ++j) acc[i][j] = 0.f;

    for (int kc = 0; kc < D_DIM; kc += KC) {
        __syncthreads();
        // Stage 64 rows x 128 k, transposed. Per wave: fixed k4, lane = row ->
        // consecutive LDS addresses per ds_write (conflict-free); the 4 waves
        // of the WG cover adjacent 16B chunks of each 64B line (L1-coalesced).
        #pragma unroll
        for (int i = 0; i < 8; ++i) {
            int f = tid + 256 * i;
            int r = f & 63;
            int k4 = f >> 6;
            float4 v = reinterpret_cast<const float4*>(
                X + (size_t)(wg_row0 + r) * D_DIM + kc)[k4];
            int kk = k4 * 4;
            xs[kk + 0][r] = v.x;
            xs[kk + 1][r] = v.y;
            xs[kk + 2][r] = v.z;
            xs[kk + 3][r] = v.w;
        }
        __syncthreads();
        #pragma unroll 4
        for (int k = 0; k < KC; ++k) {
            const float4* wp = reinterpret_cast<const float4*>(
                W1 + (size_t)(kc + k) * H_DIM + c0);
            float4 wa = wp[0];
            float4 wb = wp[1];
            float4 xa = *reinterpret_cast<const float4*>(&xs[k][r0]);
            float4 xb = *reinterpret_cast<const float4*>(&xs[k][r0 + 4]);
            float xr[8] = {xa.x, xa.y, xa.z, xa.w, xb.x, xb.y, xb.z, xb.w};
            float wr[8] = {wa.x, wa.y, wa.z, wa.w, wb.x, wb.y, wb.z, wb.w};
            #pragma unroll
            for (int i = 0; i < 8; ++i)
                #pragma unroll
                for (int j = 0; j < 8; ++j)
                    acc[i][j] = fmaf(xr[i], wr[j], acc[i][j]);
        }
    }

    // Epilogue: bias + exact GELU + dot with W2, reduce across the 32 threads
    // (= one width-32 shfl group) that share this thread's 8 rows.
    const float b2v = b2p[0];
    float part[8];
    #pragma unroll
    for (int i = 0; i < 8; ++i) {
        float sum = 0.f;
        #pragma unroll
        for (int j = 0; j < 8; ++j) {
            float z = acc[i][j] + b1[c0 + j];
            float g = 0.5f * z * (1.0f + erff(z * 0.70710678118654752440f));
            sum = fmaf(g, W2[c0 + j], sum);
        }
        part[i] = sum;
    }
    #pragma unroll
    for (int i = 0; i < 8; ++i) {
        float v = part[i];
        #pragma unroll
        for (int s = 16; s >= 1; s >>= 1) v += __shfl_xor(v, s, 32);
        part[i] = v;
    }
    if ((tid & 31) == 0) {
        #pragma unroll
        for (int i = 0; i < 8; ++i) {
            int row = wg_row0 + r0 + i;
            logits[row] = part[i] + b2v + base_logits[row & (N_DIM - 1)];
        }
    }
}

// ---------------- Kernel 2: softmax + top-8 + mask/importance/indices/gather ----------------
// One 256-thread block per batch row b.
__global__ __launch_bounds__(256) void softmax_topk_kernel(
    const float* __restrict__ logits,     // (B, N)
    const float* __restrict__ X,          // (B, N, D)
    float* __restrict__ out_selected,     // (B, K, D)
    float* __restrict__ out_mask,         // (B, N)
    float* __restrict__ out_importance,   // (B, N)
    float* __restrict__ out_indices)      // (B, K) as float
{
    const int b = blockIdx.x;
    const int tid = threadIdx.x;
    __shared__ float probs[N_DIM];
    __shared__ float redf[4];
    __shared__ int   redi[4];
    __shared__ int   sel_idx[K_SEL];

    float l0 = logits[b * N_DIM + tid];
    float l1 = logits[b * N_DIM + tid + 256];

    // block max
    float m = fmaxf(l0, l1);
    #pragma unroll
    for (int s = 32; s >= 1; s >>= 1) m = fmaxf(m, __shfl_xor(m, s, 64));
    if ((tid & 63) == 0) redf[tid >> 6] = m;
    __syncthreads();
    float gm = fmaxf(fmaxf(redf[0], redf[1]), fmaxf(redf[2], redf[3]));
    __syncthreads();   // redf reused below

    // block sum of exp
    float e0 = expf(l0 - gm), e1 = expf(l1 - gm);
    float ssum = e0 + e1;
    #pragma unroll
    for (int s = 32; s >= 1; s >>= 1) ssum += __shfl_xor(ssum, s, 64);
    if ((tid & 63) == 0) redf[tid >> 6] = ssum;
    __syncthreads();
    float denom = redf[0] + redf[1] + redf[2] + redf[3];
    float p0 = e0 / denom, p1 = e1 / denom;
    probs[tid] = p0;
    probs[tid + 256] = p1;
    out_importance[b * N_DIM + tid] = p0;
    out_importance[b * N_DIM + tid + 256] = p1;
    __syncthreads();

    // iterative top-8 argmax, lowest-index-first on ties (matches lax.top_k)
    for (int it = 0; it < K_SEL; ++it) {
        float v0 = probs[tid]; int i0 = tid;
        float v1 = probs[tid + 256];
        if (v1 > v0) { v0 = v1; i0 = tid + 256; }
        #pragma unroll
        for (int s = 32; s >= 1; s >>= 1) {
            float ov = __shfl_xor(v0, s, 64);
            int   oi = __shfl_xor(i0, s, 64);
            if (ov > v0 || (ov == v0 && oi < i0)) { v0 = ov; i0 = oi; }
        }
        if ((tid & 63) == 0) { redf[tid >> 6] = v0; redi[tid >> 6] = i0; }
        __syncthreads();
        if (tid == 0) {
            float bv = redf[0]; int bi = redi[0];
            for (int w = 1; w < 4; ++w)
                if (redf[w] > bv || (redf[w] == bv && redi[w] < bi)) { bv = redf[w]; bi = redi[w]; }
            sel_idx[it] = bi;
            probs[bi] = -1.0f;   // probs > 0 always, so -1 excludes
        }
        __syncthreads();
    }

    // mask (membership test, no scatter race)
    float mk0 = 0.f, mk1 = 0.f;
    #pragma unroll
    for (int i = 0; i < K_SEL; ++i) {
        if (sel_idx[i] == tid)       mk0 = 1.f;
        if (sel_idx[i] == tid + 256) mk1 = 1.f;
    }
    out_mask[b * N_DIM + tid] = mk0;
    out_mask[b * N_DIM + tid + 256] = mk1;

    if (tid < K_SEL) out_indices[b * K_SEL + tid] = (float)sel_idx[tid];

    // gather selected rows: 8 rows x 512 floats = 1024 float4, 4 per thread
    #pragma unroll
    for (int i = 0; i < 4; ++i) {
        int f = tid + 256 * i;
        int ki = f >> 7;       // 128 float4 per row
        int c4 = f & 127;
        float4 v = reinterpret_cast<const float4*>(
            X + ((size_t)b * N_DIM + sel_idx[ki]) * D_DIM)[c4];
        reinterpret_cast<float4*>(
            out_selected + ((size_t)b * K_SEL + ki) * D_DIM)[c4] = v;
    }
}

extern "C" void kernel_launch(void* const* d_in, const int* in_sizes, int n_in,
                              void* d_out, int out_size, void* d_ws, size_t ws_size,
                              hipStream_t stream) {
    const float* X           = (const float*)d_in[0];
    const float* W1          = (const float*)d_in[1];
    const float* b1          = (const float*)d_in[2];
    const float* W2          = (const float*)d_in[3];
    const float* b2          = (const float*)d_in[4];
    const float* base_logits = (const float*)d_in[5];

    float* out            = (float*)d_out;
    float* out_selected   = out;                                  // 128*8*512
    float* out_mask       = out_selected + B_DIM * K_SEL * D_DIM; // 128*512
    float* out_importance = out_mask + B_DIM * N_DIM;             // 128*512
    float* out_indices    = out_importance + B_DIM * N_DIM;       // 128*8

    float* logits = (float*)d_ws;  // 65536 floats = 256 KB scratch

    hipLaunchKernelGGL(fused_scorer_kernel,
                       dim3((B_DIM * N_DIM) / ROWS_PER_WG), dim3(256), 0, stream,
                       X, W1, b1, W2, b2, base_logits, logits);
    hipLaunchKernelGGL(softmax_topk_kernel,
                       dim3(B_DIM), dim3(256), 0, stream,
                       logits, X, out_selected, out_mask, out_importance, out_indices);
}